// Round 12
// baseline (416.234 us; speedup 1.0000x reference)
//
#include <hip/hip_runtime.h>
#include <math.h>

// Problem constants (fixed by the reference setup)
#define NPTS 262144
#define DIM 256
#define NB 16

#define S1_BLOCKS 2048
#define THREADS 256
#define RPB (NPTS / S1_BLOCKS)        // 128 contiguous rows per block
#define WAVES 4
#define ITERS (RPB / WAVES)           // 32 rows per wave

// History: R7 naive = 203us (latency-bound: coords->branch->load chain,
// VALUBusy 2%, HBM 10%). R9 LDS-staged metadata + branch-free = ~109us.
// R11 deeper MLP (16KB in flight) = ~105us — NEUTRAL => not MLP-depth-bound.
// This round: remove the two remaining serial structures:
//   (1) prologue: no coords in the hot path (2 boundary dwords only),
//   (2) epilogue: plain coalesced partial stores instead of 1M atomicAdds.
// Stage 2 gathers partials (sorted bids => ~128 contiguous matches/batch),
// computes counts analytically, and fuses the FC head + sigmoid.

__global__ __launch_bounds__(THREADS) void stage1_kernel(
    const float* __restrict__ pf,
    const float* __restrict__ scores,
    const int*   __restrict__ coords,
    float* __restrict__ partials,    // [S1_BLOCKS][DIM]
    int*   __restrict__ bids,        // [S1_BLOCKS]  (-1 = handled by slow path)
    float* __restrict__ slow_sums,   // [NB][DIM]  (atomic, rare)
    float* __restrict__ slow_counts) // [NB]
{
    __shared__ float s_score[RPB];
    __shared__ float s_part[WAVES][DIM];
    __shared__ int   s_b0, s_b1;

    const int t    = threadIdx.x;
    const int lane = t & 63;
    const int wid  = t >> 6;
    const int col4 = lane << 2;
    const int row0 = blockIdx.x * RPB;

    if (t < RPB) s_score[t] = scores[row0 + t];
    if (t == 0)  s_b0 = coords[(size_t)row0 * 4];
    if (t == 1)  s_b1 = coords[(size_t)(row0 + RPB - 1) * 4];
    __syncthreads();

    const float* base = pf + (size_t)row0 * DIM + col4;

    if (s_b0 == s_b1) {
        // ---- fast path: whole block in one segment (sorted seg) ----
        float a0 = 0.f, a1 = 0.f, a2 = 0.f, a3 = 0.f;
        #pragma unroll 8
        for (int it = 0; it < ITERS; ++it) {
            const int r   = (it << 2) + wid;     // 4 waves cover 4 consecutive rows
            const float s = s_score[r];
            const float4 f = *reinterpret_cast<const float4*>(base + (size_t)r * DIM);
            a0 = fmaf(s, f.x, a0);
            a1 = fmaf(s, f.y, a1);
            a2 = fmaf(s, f.z, a2);
            a3 = fmaf(s, f.w, a3);
        }
        *reinterpret_cast<float4*>(&s_part[wid][col4]) = make_float4(a0, a1, a2, a3);
        __syncthreads();
        // plain coalesced store of the block partial — NO atomics
        partials[(size_t)blockIdx.x * DIM + t] =
            s_part[0][t] + s_part[1][t] + s_part[2][t] + s_part[3][t];
        if (t == 0) bids[blockIdx.x] = s_b0;
    } else {
        // ---- slow path: block spans a segment boundary (<= 15 of 2048) ----
        if (t == 0) bids[blockIdx.x] = -1;
        float a0 = 0.f, a1 = 0.f, a2 = 0.f, a3 = 0.f;
        float cnt = 0.f;
        int cur_b = -1;
        for (int it = 0; it < ITERS; ++it) {
            const int r   = (it << 2) + wid;
            const int b   = coords[(size_t)(row0 + r) * 4];  // wave-uniform
            const float s = s_score[r];
            if (b != cur_b) {
                if (cur_b >= 0) {
                    float* dst = slow_sums + (size_t)cur_b * DIM + col4;
                    atomicAdd(dst + 0, a0);
                    atomicAdd(dst + 1, a1);
                    atomicAdd(dst + 2, a2);
                    atomicAdd(dst + 3, a3);
                    if (lane == 0) atomicAdd(slow_counts + cur_b, cnt);
                }
                a0 = a1 = a2 = a3 = 0.f;
                cnt = 0.f;
                cur_b = b;
            }
            const float4 f = *reinterpret_cast<const float4*>(base + (size_t)r * DIM);
            a0 = fmaf(s, f.x, a0);
            a1 = fmaf(s, f.y, a1);
            a2 = fmaf(s, f.z, a2);
            a3 = fmaf(s, f.w, a3);
            cnt += 1.f;
        }
        if (cur_b >= 0) {
            float* dst = slow_sums + (size_t)cur_b * DIM + col4;
            atomicAdd(dst + 0, a0);
            atomicAdd(dst + 1, a1);
            atomicAdd(dst + 2, a2);
            atomicAdd(dst + 3, a3);
            if (lane == 0) atomicAdd(slow_counts + cur_b, cnt);
        }
    }
}

// Stage 2: one block per batch. Gather matching partials + slow-path remainder,
// divide by count, then fused FC dot + sigmoid.
__global__ __launch_bounds__(THREADS) void stage2_kernel(
    const float* __restrict__ partials,
    const int*   __restrict__ bids,
    const float* __restrict__ slow_sums,
    const float* __restrict__ slow_counts,
    const float* __restrict__ w,
    const float* __restrict__ bias,
    float* __restrict__ out)
{
    __shared__ int   s_bids[S1_BLOCKS];       // 8 KB
    __shared__ float s_part[WAVES][DIM];      // 4 KB
    __shared__ int   s_nm[WAVES];
    __shared__ float s_red[WAVES];

    const int b    = blockIdx.x;
    const int t    = threadIdx.x;
    const int lane = t & 63;
    const int wid  = t >> 6;
    const int col4 = lane << 2;

    for (int i = t; i < S1_BLOCKS; i += THREADS) s_bids[i] = bids[i];
    __syncthreads();

    // Each wave scans a strided quarter of the blocks; lanes own 4 columns.
    float a0 = 0.f, a1 = 0.f, a2 = 0.f, a3 = 0.f;
    int nm = 0;
    for (int blk = wid; blk < S1_BLOCKS; blk += WAVES) {
        if (s_bids[blk] == b) {
            const float4 f = *reinterpret_cast<const float4*>(
                partials + (size_t)blk * DIM + col4);
            a0 += f.x; a1 += f.y; a2 += f.z; a3 += f.w;
            ++nm;
        }
    }
    *reinterpret_cast<float4*>(&s_part[wid][col4]) = make_float4(a0, a1, a2, a3);
    if (lane == 0) s_nm[wid] = nm;
    __syncthreads();

    const float cnt = (float)RPB * (float)(s_nm[0] + s_nm[1] + s_nm[2] + s_nm[3])
                      + slow_counts[b];
    const float v = s_part[0][t] + s_part[1][t] + s_part[2][t] + s_part[3][t]
                    + slow_sums[(size_t)b * DIM + t];

    // fused head: p_b = sigmoid( (v/cnt) . w + bias )
    float p = (v / cnt) * w[t];
    #pragma unroll
    for (int off = 32; off > 0; off >>= 1)
        p += __shfl_down(p, off, 64);
    if (lane == 0) s_red[wid] = p;
    __syncthreads();
    if (t == 0) {
        const float P = s_red[0] + s_red[1] + s_red[2] + s_red[3] + bias[0];
        out[b] = 1.f / (1.f + expf(-P));
    }
}

extern "C" void kernel_launch(void* const* d_in, const int* in_sizes, int n_in,
                              void* d_out, int out_size, void* d_ws, size_t ws_size,
                              hipStream_t stream) {
    const float* pf      = (const float*)d_in[0];   // [N][D] f32
    const float* scores  = (const float*)d_in[1];   // [N] f32
    const int*   coords  = (const int*)d_in[2];     // [N][4] i32 (col 0 = sorted batch idx)
    const float* fc_w    = (const float*)d_in[3];   // [1][D] f32
    const float* fc_b    = (const float*)d_in[4];   // [1] f32
    (void)in_sizes; (void)n_in; (void)out_size; (void)ws_size;

    float* partials    = (float*)d_ws;                          // 2 MB
    int*   bids        = (int*)(partials + (size_t)S1_BLOCKS * DIM);
    float* slow_sums   = (float*)(bids + S1_BLOCKS);            // 16 KB
    float* slow_counts = slow_sums + (size_t)NB * DIM;          // 64 B
    float* out         = (float*)d_out;                         // [NB][1] f32

    // Only the (rare) slow-path accumulators need zeroing; partials/bids are
    // fully written by stage 1, out by stage 2.
    hipMemsetAsync(slow_sums, 0, (size_t)(NB * DIM + NB) * sizeof(float), stream);

    stage1_kernel<<<S1_BLOCKS, THREADS, 0, stream>>>(
        pf, scores, coords, partials, bids, slow_sums, slow_counts);
    stage2_kernel<<<NB, THREADS, 0, stream>>>(
        partials, bids, slow_sums, slow_counts, fc_w, fc_b, out);
}